// Round 1
// baseline (478.605 us; speedup 1.0000x reference)
//
#include <hip/hip_runtime.h>

// VectorQuantizer: z (32, 64, 4096) f32, emb (1024, 64) f32.
// For each of 131072 column-vectors of z, find argmin_j ||z - emb_j||^2 and
// output emb[argmin] back in (BS, C, SEQ) layout.
//
// Numerics: must match numpy's f32 argmin (threshold = 2% of 1/64; any index
// flip fails). We replicate the reference rounding:
//   d = fadd(z_sq, e_sq) - 2*dot   (2*dot exact; final sub single-rounded)
// z_sq / e_sq use numpy's pairwise-sum order for n=64 (8 accumulators +
// reduction tree), with squares rounded before accumulation (no FMA there).
// dot is a single sequential FMA chain over k=0..63 (BLAS-like).
// Strict '<' + ascending j = numpy argmin first-index tie-break.

constexpr int N_EMB = 1024;
constexpr int CDIM  = 64;
constexpr int SEQ   = 4096;
constexpr int BS    = 32;
constexpr int NROWS = BS * SEQ;   // 131072

__global__ __launch_bounds__(256, 2) void vq_kernel(
    const float* __restrict__ z,
    const float* __restrict__ emb,
    float* __restrict__ out)
{
    __shared__ float esq[N_EMB];

    // ---- per-block e_sq in numpy pairwise order (n=64) ----
    for (int j = threadIdx.x; j < N_EMB; j += 256) {
        const float* e = emb + j * CDIM;
        float r[8];
        #pragma unroll
        for (int t = 0; t < 8; ++t) r[t] = __fmul_rn(e[t], e[t]);
        #pragma unroll
        for (int i = 8; i < 64; i += 8) {
            #pragma unroll
            for (int t = 0; t < 8; ++t)
                r[t] = __fadd_rn(r[t], __fmul_rn(e[i + t], e[i + t]));
        }
        esq[j] = __fadd_rn(
                    __fadd_rn(__fadd_rn(r[0], r[1]), __fadd_rn(r[2], r[3])),
                    __fadd_rn(__fadd_rn(r[4], r[5]), __fadd_rn(r[6], r[7])));
    }
    __syncthreads();

    const int row = blockIdx.x * 256 + threadIdx.x;   // row in [0, 131072)
    const int b = row >> 12;          // / SEQ
    const int s = row & (SEQ - 1);

    // ---- load this thread's z vector (lane-consecutive s -> coalesced) ----
    const float* zp = z + (size_t)b * CDIM * SEQ + s;
    float zv[CDIM];
    #pragma unroll
    for (int k = 0; k < CDIM; ++k) zv[k] = zp[(size_t)k * SEQ];

    // ---- z_sq in numpy pairwise order ----
    float r[8];
    #pragma unroll
    for (int t = 0; t < 8; ++t) r[t] = __fmul_rn(zv[t], zv[t]);
    #pragma unroll
    for (int i = 8; i < 64; i += 8) {
        #pragma unroll
        for (int t = 0; t < 8; ++t)
            r[t] = __fadd_rn(r[t], __fmul_rn(zv[i + t], zv[i + t]));
    }
    const float zsq = __fadd_rn(
                        __fadd_rn(__fadd_rn(r[0], r[1]), __fadd_rn(r[2], r[3])),
                        __fadd_rn(__fadd_rn(r[4], r[5]), __fadd_rn(r[6], r[7])));

    // ---- scan all 1024 codes: d = (zsq + esq_j) - 2*dot ----
    float dmin = INFINITY;
    int   jmin = 0;
    #pragma unroll 4
    for (int j = 0; j < N_EMB; ++j) {
        const float* e = emb + j * CDIM;   // wave-uniform -> scalar loads
        float acc = 0.0f;
        #pragma unroll
        for (int k = 0; k < CDIM; ++k)
            acc = __fmaf_rn(zv[k], e[k], acc);
        const float d = __fsub_rn(__fadd_rn(zsq, esq[j]), __fmul_rn(2.0f, acc));
        if (d < dmin) { dmin = d; jmin = j; }   // strict < keeps first index
    }

    // ---- gather emb[jmin] and scatter to (b, c, s) layout ----
    const float4* ej = reinterpret_cast<const float4*>(emb + (size_t)jmin * CDIM);
    float* op = out + (size_t)b * CDIM * SEQ + s;
    #pragma unroll
    for (int q = 0; q < CDIM / 4; ++q) {
        const float4 v = ej[q];            // 256B rows, L1/L2-hot
        op[(size_t)(4 * q + 0) * SEQ] = v.x;
        op[(size_t)(4 * q + 1) * SEQ] = v.y;
        op[(size_t)(4 * q + 2) * SEQ] = v.z;
        op[(size_t)(4 * q + 3) * SEQ] = v.w;
    }
}

extern "C" void kernel_launch(void* const* d_in, const int* in_sizes, int n_in,
                              void* d_out, int out_size, void* d_ws, size_t ws_size,
                              hipStream_t stream)
{
    const float* z   = (const float*)d_in[0];
    const float* emb = (const float*)d_in[1];
    float* out = (float*)d_out;

    const int grid = NROWS / 256;   // 512 blocks
    vq_kernel<<<grid, 256, 0, stream>>>(z, emb, out);
}